// Round 4
// baseline (207.241 us; speedup 1.0000x reference)
//
#include <hip/hip_runtime.h>
#include <hip/hip_bf16.h>

#define F_IN 128
#define F_OUT 64
#define BUCKET_SHIFT 7
#define BUCKET_NODES 128   // 1 << BUCKET_SHIFT
#define BUCKET_CAP 2880    // per bucket: mean 2048, sigma ~45 -> 18 sigma margin
#define CNT_STRIDE 16      // bucket counters padded to one 64B line
#define NB_MAX 800         // ceil(100000/128) = 782
#define SCAT_CHUNK 4096    // edges per scatter block -> 391 blocks (spread CUs)
#define EPT 8              // edges per thread in scatter (SCAT_CHUNK/512)
#define P1_GEMM_ROWS 64    // rows per GEMM tile
#define N_GEMM_BLOCKS 768  // persistent GEMM blocks (~2 tiles each)
#define LDK 136            // padded K stride in LDS (elems): 272B = 17*16B
#define SA_EPT 6           // region entries per thread in sort_agg (2880/512)

typedef __attribute__((ext_vector_type(8))) short bf16x8;
typedef __attribute__((ext_vector_type(4))) float f32x4;

__device__ inline short bf16_bits(float f) {
  __hip_bfloat16 h = __float2bfloat16(f);
  return *reinterpret_cast<short*>(&h);
}

// ---------------- phase 1: fused {bucket scatter | persistent GEMM} ---------
// blockIdx < n_scat_blocks  -> scatter body (edges held in REGISTERS)
// blockIdx >= n_scat_blocks -> persistent MFMA GEMM: stage W once, then a
//   barrier-free tile loop (Bs read-only; A-frags direct from global x).
// Union LDS = max(17.4KB Bs, 6.4KB hist) = 17.4KB -> wave-capped 4 blocks/CU.
union Phase1Smem {
  struct { short Bs[F_OUT][LDK]; } g;                  // 17408 B
  struct { int lhist[NB_MAX]; int lcur[NB_MAX]; } s;   //  6400 B
};

__global__ __launch_bounds__(512, 6) void gcn_phase1_kernel(
    const float* __restrict__ x, const float* __restrict__ w,
    __hip_bfloat16* __restrict__ support,
    const int* __restrict__ esrc, const int* __restrict__ edst,
    const float* __restrict__ ew, int* __restrict__ bcount,
    int2* __restrict__ region, int n_nodes, int n_edges, int nb,
    int n_scat_blocks, int ntiles) {
  __shared__ Phase1Smem sm;
  const int tid = threadIdx.x;

  if ((int)blockIdx.x < n_scat_blocks) {
    // ---------------- scatter body: edges in registers ----------------
    const int e0 = blockIdx.x * SCAT_CHUNK;
    const int n_local = min(SCAT_CHUNK, n_edges - e0);

    for (int i = tid; i < nb; i += 512) sm.s.lhist[i] = 0;
    __syncthreads();
    int dreg[EPT];
#pragma unroll
    for (int p = 0; p < EPT; ++p) {
      const int i = tid + p * 512;
      dreg[p] = -1;
      if (i < n_local) {
        const int d = edst[e0 + i];
        dreg[p] = d;
        atomicAdd(&sm.s.lhist[d >> BUCKET_SHIFT], 1);
      }
    }
    __syncthreads();
    for (int b = tid; b < nb; b += 512) {
      const int c = sm.s.lhist[b];
      sm.s.lcur[b] = c ? atomicAdd(&bcount[b * CNT_STRIDE], c) : 0;
    }
    __syncthreads();
#pragma unroll
    for (int p = 0; p < EPT; ++p) {
      const int i = tid + p * 512;
      const int d = dreg[p];
      if (d >= 0) {
        const int b = d >> BUCKET_SHIFT;
        const int pos = atomicAdd(&sm.s.lcur[b], 1);  // native int LDS atomic
        if (pos < BUCKET_CAP) {
          region[(size_t)b * BUCKET_CAP + pos] = make_int2(
              (esrc[e0 + i] << BUCKET_SHIFT) | (d & (BUCKET_NODES - 1)),
              __float_as_int(ew[e0 + i]));
        }
      }
    }
  } else {
    // -------- persistent GEMM: stage W once, loop tiles barrier-free --------
    const int gbid = (int)blockIdx.x - n_scat_blocks;
#pragma unroll
    for (int i = 0; i < F_IN * F_OUT / 512; ++i) {  // 16 iters
      const int idx = tid + i * 512;
      sm.g.Bs[idx & 63][idx >> 6] = bf16_bits(w[idx]);
    }
    __syncthreads();  // Bs ready; read-only hereafter -> no more barriers

    const int lane = tid & 63;
    const int wid = tid >> 6;
    const int wr0 = (wid >> 1) * 16;  // row group
    const int wc0 = (wid & 1) * 32;   // col half
    const int m = lane & 15;
    const int quad = lane >> 4;

    for (int t = gbid; t < ntiles; t += N_GEMM_BLOCKS) {
      const int block_row = t * P1_GEMM_ROWS;
      const int row = block_row + wr0 + m;

      bf16x8 afrag[4];
      if (row < n_nodes) {
        const float4* xr = (const float4*)(x + (size_t)row * F_IN);
#pragma unroll
        for (int ks = 0; ks < 4; ++ks) {
          const float4 v0 = xr[ks * 8 + quad * 2];
          const float4 v1 = xr[ks * 8 + quad * 2 + 1];
          bf16x8 a;
          a[0] = bf16_bits(v0.x); a[1] = bf16_bits(v0.y);
          a[2] = bf16_bits(v0.z); a[3] = bf16_bits(v0.w);
          a[4] = bf16_bits(v1.x); a[5] = bf16_bits(v1.y);
          a[6] = bf16_bits(v1.z); a[7] = bf16_bits(v1.w);
          afrag[ks] = a;
        }
      } else {
#pragma unroll
        for (int ks = 0; ks < 4; ++ks) afrag[ks] = (bf16x8)0;
      }

      f32x4 acc0 = {0.f, 0.f, 0.f, 0.f};
      f32x4 acc1 = {0.f, 0.f, 0.f, 0.f};
#pragma unroll
      for (int ks = 0; ks < 4; ++ks) {
        const int ko = ks * 32 + quad * 8;
        const bf16x8 b0 = *(const bf16x8*)&sm.g.Bs[wc0 + m][ko];
        const bf16x8 b1 = *(const bf16x8*)&sm.g.Bs[wc0 + 16 + m][ko];
        acc0 = __builtin_amdgcn_mfma_f32_16x16x32_bf16(afrag[ks], b0, acc0, 0, 0, 0);
        acc1 = __builtin_amdgcn_mfma_f32_16x16x32_bf16(afrag[ks], b1, acc1, 0, 0, 0);
      }
#pragma unroll
      for (int r = 0; r < 4; ++r) {
        const int orow = block_row + wr0 + quad * 4 + r;
        if (orow < n_nodes) {
          __hip_bfloat16* op = support + (size_t)orow * F_OUT;
          op[wc0 + m]      = __float2bfloat16(acc0[r]);
          op[wc0 + 16 + m] = __float2bfloat16(acc1[r]);
        }
      }
    }
  }
}

// -------- pass 2: per-bucket LDS sort + in-kernel aggregate ------------------
// region read ONCE into registers; histogram (4-way privatized) + scatter from
// regs. Gather remapped to 8 row-slots x 8 channel-groups: each lane loads
// 16B (uint4) -> one VMEM inst gathers 8 full support rows per wave.
__global__ __launch_bounds__(512, 6) void gcn_sort_agg_kernel(
    const __hip_bfloat16* __restrict__ support,
    const int2* __restrict__ region, const int* __restrict__ bcount,
    const float* __restrict__ bias, float* __restrict__ out, int n_nodes) {
  __shared__ int2 outb[BUCKET_CAP];          // 23040 B
  __shared__ int hist4[4][BUCKET_NODES];     //  2048 B
  __shared__ int nbeg[BUCKET_NODES];
  __shared__ int lcur[BUCKET_NODES];
  const int b = blockIdx.x;
  const int tid = threadIdx.x;
  const int lane = tid & 63;
  const int hq = (tid >> 7) & 3;

  int cnt = bcount[b * CNT_STRIDE];
  cnt = (cnt < BUCKET_CAP ? cnt : BUCKET_CAP);
  const int2* reg = region + (size_t)b * BUCKET_CAP;

  for (int i = tid; i < 4 * BUCKET_NODES; i += 512) ((int*)hist4)[i] = 0;
  __syncthreads();
  int2 ereg[SA_EPT];
#pragma unroll
  for (int p = 0; p < SA_EPT; ++p) {          // single region read -> regs
    const int i = tid + p * 512;
    ereg[p].x = -1;
    if (i < cnt) {
      ereg[p] = reg[i];
      atomicAdd(&hist4[hq][ereg[p].x & (BUCKET_NODES - 1)], 1);
    }
  }
  __syncthreads();
  if (tid < 64) {                             // exclusive scan of 128 counts
    const int v0 = hist4[0][lane] + hist4[1][lane] + hist4[2][lane] +
                   hist4[3][lane];
    const int l1 = 64 + lane;
    const int v1 = hist4[0][l1] + hist4[1][l1] + hist4[2][l1] + hist4[3][l1];
    int s0 = v0;
#pragma unroll
    for (int off = 1; off < 64; off <<= 1) {
      const int t = __shfl_up(s0, off, 64);
      if (lane >= off) s0 += t;
    }
    const int tot0 = __shfl(s0, 63, 64);
    int s1 = v1;
#pragma unroll
    for (int off = 1; off < 64; off <<= 1) {
      const int t = __shfl_up(s1, off, 64);
      if (lane >= off) s1 += t;
    }
    s1 += tot0;
    nbeg[lane] = s0 - v0;
    nbeg[l1] = s1 - v1;
    lcur[lane] = s0 - v0;
    lcur[l1] = s1 - v1;
  }
  __syncthreads();
#pragma unroll
  for (int p = 0; p < SA_EPT; ++p) {          // scatter into outb from regs
    if (ereg[p].x >= 0) {
      const int pos = atomicAdd(&lcur[ereg[p].x & (BUCKET_NODES - 1)], 1);
      outb[pos] = make_int2(ereg[p].x >> BUCKET_SHIFT, ereg[p].y);
    }
  }
  __syncthreads();                            // lcur[n] now == run end

  // aggregate: wave owns 16 nodes; lane = (row-slot r=lane>>3, chan-group
  // cg=lane&7). Each lane loads uint4 = 8 bf16 channels: wave gathers 8 rows
  // per VMEM inst. Reduce over 8 slots via shfl_xor(8,16,32); float4 stores.
  const int wid = tid >> 6;
  const int r = lane >> 3;
  const int cg = lane & 7;
  const ushort* sup = (const ushort*)support;
  const float4 bb0 = *(const float4*)(bias + cg * 8);
  const float4 bb1 = *(const float4*)(bias + cg * 8 + 4);
  for (int nl = wid * 16; nl < wid * 16 + 16; ++nl) {
    const int g = (b << BUCKET_SHIFT) + nl;
    if (g >= n_nodes) break;  // uniform across wave
    const int s = nbeg[nl];
    const int e = lcur[nl];
    float acc[8] = {0.f, 0.f, 0.f, 0.f, 0.f, 0.f, 0.f, 0.f};
    for (int j = s; j < e; j += 8) {
      const int jr = j + r;
      const bool valid = jr < e;
      const int2 meta = outb[valid ? jr : e - 1];
      const float wv = valid ? __int_as_float(meta.y) : 0.f;
      const uint4 d = *(const uint4*)(sup + (size_t)meta.x * F_OUT + cg * 8);
      acc[0] = fmaf(__uint_as_float(d.x << 16), wv, acc[0]);
      acc[1] = fmaf(__uint_as_float(d.x & 0xffff0000u), wv, acc[1]);
      acc[2] = fmaf(__uint_as_float(d.y << 16), wv, acc[2]);
      acc[3] = fmaf(__uint_as_float(d.y & 0xffff0000u), wv, acc[3]);
      acc[4] = fmaf(__uint_as_float(d.z << 16), wv, acc[4]);
      acc[5] = fmaf(__uint_as_float(d.z & 0xffff0000u), wv, acc[5]);
      acc[6] = fmaf(__uint_as_float(d.w << 16), wv, acc[6]);
      acc[7] = fmaf(__uint_as_float(d.w & 0xffff0000u), wv, acc[7]);
    }
#pragma unroll
    for (int i = 0; i < 8; ++i) {  // reduce over the 8 row-slots
      float v = acc[i];
      v += __shfl_xor(v, 8, 64);
      v += __shfl_xor(v, 16, 64);
      v += __shfl_xor(v, 32, 64);
      acc[i] = v;
    }
    if (r == 0) {
      float* op = out + (size_t)g * F_OUT + cg * 8;
      float4 o0, o1;
      o0.x = acc[0] + bb0.x; o0.y = acc[1] + bb0.y;
      o0.z = acc[2] + bb0.z; o0.w = acc[3] + bb0.w;
      o1.x = acc[4] + bb1.x; o1.y = acc[5] + bb1.y;
      o1.z = acc[6] + bb1.z; o1.w = acc[7] + bb1.w;
      *(float4*)op = o0;
      *(float4*)(op + 4) = o1;
    }
  }
}

extern "C" void kernel_launch(void* const* d_in, const int* in_sizes, int n_in,
                              void* d_out, int out_size, void* d_ws, size_t ws_size,
                              hipStream_t stream) {
  const float* x    = (const float*)d_in[0];
  const float* ew   = (const float*)d_in[1];
  const float* w    = (const float*)d_in[2];
  const float* bias = (const float*)d_in[3];
  const int*   esrc = (const int*)d_in[4];
  const int*   edst = (const int*)d_in[5];
  float* out = (float*)d_out;

  const int n_nodes = in_sizes[0] / F_IN;
  const int n_edges = in_sizes[4];
  const int nb = (n_nodes + BUCKET_NODES - 1) >> BUCKET_SHIFT;

  // workspace: bcount | region | support  (~31 MB)
  char* ws = (char*)d_ws;
  size_t off = 0;
  auto alloc = [&](size_t bytes) {
    size_t o = off;
    off += (bytes + 255) / 256 * 256;
    return o;
  };
  const size_t off_bcount  = alloc((size_t)nb * CNT_STRIDE * sizeof(int));
  const size_t off_region  = alloc((size_t)nb * BUCKET_CAP * sizeof(int2));
  const size_t off_support = alloc((size_t)n_nodes * F_OUT * sizeof(__hip_bfloat16));
  (void)off_support;

  int*  bcount = (int*)(ws + off_bcount);
  int2* region = (int2*)(ws + off_region);
  __hip_bfloat16* support = (__hip_bfloat16*)(ws + off_support);

  const int scat_blocks = (n_edges + SCAT_CHUNK - 1) / SCAT_CHUNK;
  const int ntiles = (n_nodes + P1_GEMM_ROWS - 1) / P1_GEMM_ROWS;

  hipMemsetAsync(bcount, 0, (size_t)nb * CNT_STRIDE * sizeof(int), stream);
  gcn_phase1_kernel<<<scat_blocks + N_GEMM_BLOCKS, 512, 0, stream>>>(
      x, w, support, esrc, edst, ew, bcount, region, n_nodes, n_edges, nb,
      scat_blocks, ntiles);
  gcn_sort_agg_kernel<<<nb, 512, 0, stream>>>(support, region, bcount, bias,
                                              out, n_nodes);
}

// Round 5
// 196.498 us; speedup vs baseline: 1.0547x; 1.0547x over previous
//
#include <hip/hip_runtime.h>
#include <hip/hip_bf16.h>

#define F_IN 128
#define F_OUT 64
#define BUCKET_SHIFT 7
#define BUCKET_NODES 128   // 1 << BUCKET_SHIFT
#define BUCKET_CAP 2880    // per bucket: mean 2048, sigma ~45 -> 18 sigma margin
#define CNT_STRIDE 16      // bucket counters padded to one 64B line
#define NB_MAX 800         // ceil(100000/128) = 782
#define SCAT_CHUNK 8192    // edges per scatter block (8192: run len ~10 edges,
                           // low region write amplification; 4096 was +16MB)
#define EPT 8              // edges per thread in scatter (SCAT_CHUNK/1024)
#define P1_GEMM_ROWS 128   // rows per GEMM tile (1024 thr: 8 row-grp x 2 col)
#define LDK 136            // padded K stride in LDS (elems): 272B = 17*16B
#define SA_EPT 3           // region entries per thread in sort_agg (2880/1024)

typedef __attribute__((ext_vector_type(8))) short bf16x8;
typedef __attribute__((ext_vector_type(4))) float f32x4;

__device__ inline short bf16_bits(float f) {
  __hip_bfloat16 h = __float2bfloat16(f);
  return *reinterpret_cast<short*>(&h);
}

// ---------------- phase 1: fused {bucket scatter | GEMM}, 1024 threads ------
// blockIdx < n_scat_blocks  -> scatter body (edges held in registers)
// blockIdx >= n_scat_blocks -> MFMA GEMM body (support = bf16(X @ W));
//   A-frags direct from global x (8 contiguous K elems/lane), W staged once.
// 1024-thr blocks: serial work per thread halves, 16 waves/block -> 2 blocks/CU
// = 32 waves/CU (max). Union LDS = max(17.4KB Bs, 6.4KB hist) = 17.4KB.
union Phase1Smem {
  struct { short Bs[F_OUT][LDK]; } g;                  // 17408 B
  struct { int lhist[NB_MAX]; int lcur[NB_MAX]; } s;   //  6400 B
};

__global__ __launch_bounds__(1024, 2) void gcn_phase1_kernel(
    const float* __restrict__ x, const float* __restrict__ w,
    __hip_bfloat16* __restrict__ support,
    const int* __restrict__ esrc, const int* __restrict__ edst,
    const float* __restrict__ ew, int* __restrict__ bcount,
    int2* __restrict__ region, int n_nodes, int n_edges, int nb,
    int n_scat_blocks) {
  __shared__ Phase1Smem sm;
  const int tid = threadIdx.x;

  if ((int)blockIdx.x < n_scat_blocks) {
    // ---------------- scatter body: edges in registers ----------------
    const int e0 = blockIdx.x * SCAT_CHUNK;
    const int n_local = min(SCAT_CHUNK, n_edges - e0);

    for (int i = tid; i < nb; i += 1024) sm.s.lhist[i] = 0;
    __syncthreads();
    int dreg[EPT];
#pragma unroll
    for (int p = 0; p < EPT; ++p) {
      const int i = tid + p * 1024;
      dreg[p] = -1;
      if (i < n_local) {
        const int d = edst[e0 + i];
        dreg[p] = d;
        atomicAdd(&sm.s.lhist[d >> BUCKET_SHIFT], 1);
      }
    }
    __syncthreads();
    for (int b = tid; b < nb; b += 1024) {
      const int c = sm.s.lhist[b];
      sm.s.lcur[b] = c ? atomicAdd(&bcount[b * CNT_STRIDE], c) : 0;
    }
    __syncthreads();
#pragma unroll
    for (int p = 0; p < EPT; ++p) {
      const int i = tid + p * 1024;
      const int d = dreg[p];
      if (d >= 0) {
        const int b = d >> BUCKET_SHIFT;
        const int pos = atomicAdd(&sm.s.lcur[b], 1);  // native int LDS atomic
        if (pos < BUCKET_CAP) {
          region[(size_t)b * BUCKET_CAP + pos] = make_int2(
              (esrc[e0 + i] << BUCKET_SHIFT) | (d & (BUCKET_NODES - 1)),
              __float_as_int(ew[e0 + i]));
        }
      }
    }
  } else {
    // ------ GEMM body: 128 rows, 16 waves = 8 row-groups x 2 col-halves -----
    const int gbid = (int)blockIdx.x - n_scat_blocks;
    const int block_row = gbid * P1_GEMM_ROWS;

#pragma unroll
    for (int i = 0; i < F_IN * F_OUT / 1024; ++i) {  // 8 iters
      const int idx = tid + i * 1024;
      sm.g.Bs[idx & 63][idx >> 6] = bf16_bits(w[idx]);
    }

    const int lane = tid & 63;
    const int wid = tid >> 6;
    const int wr0 = (wid >> 1) * 16;  // row group (0..112)
    const int wc0 = (wid & 1) * 32;   // col half
    const int m = lane & 15;
    const int quad = lane >> 4;
    const int row = block_row + wr0 + m;

    // A-fragments straight from global: 8 contiguous K elems per lane per ks.
    bf16x8 afrag[4];
    if (row < n_nodes) {
      const float4* xr = (const float4*)(x + (size_t)row * F_IN);
#pragma unroll
      for (int ks = 0; ks < 4; ++ks) {
        const float4 v0 = xr[ks * 8 + quad * 2];
        const float4 v1 = xr[ks * 8 + quad * 2 + 1];
        bf16x8 a;
        a[0] = bf16_bits(v0.x); a[1] = bf16_bits(v0.y);
        a[2] = bf16_bits(v0.z); a[3] = bf16_bits(v0.w);
        a[4] = bf16_bits(v1.x); a[5] = bf16_bits(v1.y);
        a[6] = bf16_bits(v1.z); a[7] = bf16_bits(v1.w);
        afrag[ks] = a;
      }
    } else {
#pragma unroll
      for (int ks = 0; ks < 4; ++ks) afrag[ks] = (bf16x8)0;
    }
    __syncthreads();  // Bs ready

    f32x4 acc0 = {0.f, 0.f, 0.f, 0.f};
    f32x4 acc1 = {0.f, 0.f, 0.f, 0.f};
#pragma unroll
    for (int ks = 0; ks < 4; ++ks) {
      const int ko = ks * 32 + quad * 8;
      const bf16x8 b0 = *(const bf16x8*)&sm.g.Bs[wc0 + m][ko];
      const bf16x8 b1 = *(const bf16x8*)&sm.g.Bs[wc0 + 16 + m][ko];
      acc0 = __builtin_amdgcn_mfma_f32_16x16x32_bf16(afrag[ks], b0, acc0, 0, 0, 0);
      acc1 = __builtin_amdgcn_mfma_f32_16x16x32_bf16(afrag[ks], b1, acc1, 0, 0, 0);
    }
#pragma unroll
    for (int r = 0; r < 4; ++r) {
      const int orow = block_row + wr0 + quad * 4 + r;
      if (orow < n_nodes) {
        __hip_bfloat16* op = support + (size_t)orow * F_OUT;
        op[wc0 + m]      = __float2bfloat16(acc0[r]);
        op[wc0 + 16 + m] = __float2bfloat16(acc1[r]);
      }
    }
  }
}

// -------- pass 2: per-bucket LDS sort + in-kernel aggregate, 1024 thr --------
// 16 waves x 8 serial nodes each (was 8x16): halves the per-wave serial node
// chain, doubles resident waves to hide LLC gather latency.
// region read once into regs; 4-way privatized histogram; gather remapped to
// 8 row-slots x 8 channel-groups (16B/lane -> 8 support rows per VMEM inst).
__global__ __launch_bounds__(1024, 2) void gcn_sort_agg_kernel(
    const __hip_bfloat16* __restrict__ support,
    const int2* __restrict__ region, const int* __restrict__ bcount,
    const float* __restrict__ bias, float* __restrict__ out, int n_nodes) {
  __shared__ int2 outb[BUCKET_CAP];          // 23040 B
  __shared__ int hist4[4][BUCKET_NODES];     //  2048 B
  __shared__ int nbeg[BUCKET_NODES];
  __shared__ int lcur[BUCKET_NODES];
  const int b = blockIdx.x;
  const int tid = threadIdx.x;
  const int lane = tid & 63;
  const int hq = (tid >> 6) & 3;  // wave-granular hist copy

  int cnt = bcount[b * CNT_STRIDE];
  cnt = (cnt < BUCKET_CAP ? cnt : BUCKET_CAP);
  const int2* reg = region + (size_t)b * BUCKET_CAP;

  for (int i = tid; i < 4 * BUCKET_NODES; i += 1024) ((int*)hist4)[i] = 0;
  __syncthreads();
  int2 ereg[SA_EPT];
#pragma unroll
  for (int p = 0; p < SA_EPT; ++p) {          // single region read -> regs
    const int i = tid + p * 1024;
    ereg[p].x = -1;
    if (i < cnt) {
      ereg[p] = reg[i];
      atomicAdd(&hist4[hq][ereg[p].x & (BUCKET_NODES - 1)], 1);
    }
  }
  __syncthreads();
  if (tid < 64) {                             // exclusive scan of 128 counts
    const int v0 = hist4[0][lane] + hist4[1][lane] + hist4[2][lane] +
                   hist4[3][lane];
    const int l1 = 64 + lane;
    const int v1 = hist4[0][l1] + hist4[1][l1] + hist4[2][l1] + hist4[3][l1];
    int s0 = v0;
#pragma unroll
    for (int off = 1; off < 64; off <<= 1) {
      const int t = __shfl_up(s0, off, 64);
      if (lane >= off) s0 += t;
    }
    const int tot0 = __shfl(s0, 63, 64);
    int s1 = v1;
#pragma unroll
    for (int off = 1; off < 64; off <<= 1) {
      const int t = __shfl_up(s1, off, 64);
      if (lane >= off) s1 += t;
    }
    s1 += tot0;
    nbeg[lane] = s0 - v0;
    nbeg[l1] = s1 - v1;
    lcur[lane] = s0 - v0;
    lcur[l1] = s1 - v1;
  }
  __syncthreads();
#pragma unroll
  for (int p = 0; p < SA_EPT; ++p) {          // scatter into outb from regs
    if (ereg[p].x >= 0) {
      const int pos = atomicAdd(&lcur[ereg[p].x & (BUCKET_NODES - 1)], 1);
      outb[pos] = make_int2(ereg[p].x >> BUCKET_SHIFT, ereg[p].y);
    }
  }
  __syncthreads();                            // lcur[n] now == run end

  // aggregate: wave owns 8 nodes; lane = (row-slot r=lane>>3, chan-grp lane&7)
  const int wid = tid >> 6;
  const int r = lane >> 3;
  const int cg = lane & 7;
  const ushort* sup = (const ushort*)support;
  const float4 bb0 = *(const float4*)(bias + cg * 8);
  const float4 bb1 = *(const float4*)(bias + cg * 8 + 4);
  for (int nl = wid * 8; nl < wid * 8 + 8; ++nl) {
    const int g = (b << BUCKET_SHIFT) + nl;
    if (g >= n_nodes) break;  // uniform across wave
    const int s = nbeg[nl];
    const int e = lcur[nl];
    float acc[8] = {0.f, 0.f, 0.f, 0.f, 0.f, 0.f, 0.f, 0.f};
    for (int j = s; j < e; j += 8) {
      const int jr = j + r;
      const bool valid = jr < e;
      const int2 meta = outb[valid ? jr : e - 1];
      const float wv = valid ? __int_as_float(meta.y) : 0.f;
      const uint4 d = *(const uint4*)(sup + (size_t)meta.x * F_OUT + cg * 8);
      acc[0] = fmaf(__uint_as_float(d.x << 16), wv, acc[0]);
      acc[1] = fmaf(__uint_as_float(d.x & 0xffff0000u), wv, acc[1]);
      acc[2] = fmaf(__uint_as_float(d.y << 16), wv, acc[2]);
      acc[3] = fmaf(__uint_as_float(d.y & 0xffff0000u), wv, acc[3]);
      acc[4] = fmaf(__uint_as_float(d.z << 16), wv, acc[4]);
      acc[5] = fmaf(__uint_as_float(d.z & 0xffff0000u), wv, acc[5]);
      acc[6] = fmaf(__uint_as_float(d.w << 16), wv, acc[6]);
      acc[7] = fmaf(__uint_as_float(d.w & 0xffff0000u), wv, acc[7]);
    }
#pragma unroll
    for (int i = 0; i < 8; ++i) {  // reduce over the 8 row-slots
      float v = acc[i];
      v += __shfl_xor(v, 8, 64);
      v += __shfl_xor(v, 16, 64);
      v += __shfl_xor(v, 32, 64);
      acc[i] = v;
    }
    if (r == 0) {
      float* op = out + (size_t)g * F_OUT + cg * 8;
      float4 o0, o1;
      o0.x = acc[0] + bb0.x; o0.y = acc[1] + bb0.y;
      o0.z = acc[2] + bb0.z; o0.w = acc[3] + bb0.w;
      o1.x = acc[4] + bb1.x; o1.y = acc[5] + bb1.y;
      o1.z = acc[6] + bb1.z; o1.w = acc[7] + bb1.w;
      *(float4*)op = o0;
      *(float4*)(op + 4) = o1;
    }
  }
}

extern "C" void kernel_launch(void* const* d_in, const int* in_sizes, int n_in,
                              void* d_out, int out_size, void* d_ws, size_t ws_size,
                              hipStream_t stream) {
  const float* x    = (const float*)d_in[0];
  const float* ew   = (const float*)d_in[1];
  const float* w    = (const float*)d_in[2];
  const float* bias = (const float*)d_in[3];
  const int*   esrc = (const int*)d_in[4];
  const int*   edst = (const int*)d_in[5];
  float* out = (float*)d_out;

  const int n_nodes = in_sizes[0] / F_IN;
  const int n_edges = in_sizes[4];
  const int nb = (n_nodes + BUCKET_NODES - 1) >> BUCKET_SHIFT;

  // workspace: bcount | region | support  (~31 MB)
  char* ws = (char*)d_ws;
  size_t off = 0;
  auto alloc = [&](size_t bytes) {
    size_t o = off;
    off += (bytes + 255) / 256 * 256;
    return o;
  };
  const size_t off_bcount  = alloc((size_t)nb * CNT_STRIDE * sizeof(int));
  const size_t off_region  = alloc((size_t)nb * BUCKET_CAP * sizeof(int2));
  const size_t off_support = alloc((size_t)n_nodes * F_OUT * sizeof(__hip_bfloat16));
  (void)off_support;

  int*  bcount = (int*)(ws + off_bcount);
  int2* region = (int2*)(ws + off_region);
  __hip_bfloat16* support = (__hip_bfloat16*)(ws + off_support);

  const int scat_blocks = (n_edges + SCAT_CHUNK - 1) / SCAT_CHUNK;
  const int gemm_blocks = (n_nodes + P1_GEMM_ROWS - 1) / P1_GEMM_ROWS;

  hipMemsetAsync(bcount, 0, (size_t)nb * CNT_STRIDE * sizeof(int), stream);
  gcn_phase1_kernel<<<scat_blocks + gemm_blocks, 1024, 0, stream>>>(
      x, w, support, esrc, edst, ew, bcount, region, n_nodes, n_edges, nb,
      scat_blocks);
  gcn_sort_agg_kernel<<<nb, 1024, 0, stream>>>(support, region, bcount, bias,
                                               out, n_nodes);
}

// Round 6
// 194.910 us; speedup vs baseline: 1.0633x; 1.0081x over previous
//
#include <hip/hip_runtime.h>
#include <hip/hip_bf16.h>

#define F_IN 128
#define F_OUT 64
#define BUCKET_SHIFT 7
#define BUCKET_NODES 128   // 1 << BUCKET_SHIFT
#define BUCKET_CAP 2880    // mean 2048 + pad ~343 + 9 sigma margin
#define CNT_STRIDE 16      // bucket counters padded to one 64B line
#define NB_MAX 800         // ceil(100000/128) = 782
#define SCAT_CHUNK 16384   // 98 scatter blocks; big runs -> less line padding
#define EPT 16             // edges per thread in scatter (SCAT_CHUNK/1024)
#define P1_GEMM_ROWS 128   // rows per GEMM tile (1024 thr: 8 row-grp x 2 col)
#define LDK 136            // padded K stride in LDS (elems): 272B = 17*16B
#define SA_EPT 3           // region entries per thread in sort_agg (2880/1024)

typedef __attribute__((ext_vector_type(8))) short bf16x8;
typedef __attribute__((ext_vector_type(4))) float f32x4;

__device__ inline short bf16_bits(float f) {
  __hip_bfloat16 h = __float2bfloat16(f);
  return *reinterpret_cast<short*>(&h);
}

// ---------------- phase 1: fused {bucket scatter | GEMM}, 1024 threads ------
// Scatter reserves LINE-ALIGNED runs: bucket reservations rounded up to 8
// entries (64B), pad slots filled with (src=0, ldst=pos&127, w=0) which
// contribute exactly 0 downstream. Every region 64B line is written by ONE
// block -> no cross-XCD RFO bounce (R5: WRITE_SIZE 56.5MB vs 25.6 useful).
union Phase1Smem {
  struct { short Bs[F_OUT][LDK]; } g;                  // 17408 B
  struct { int lhist[NB_MAX]; int lcur[NB_MAX]; } s;   //  6400 B
};

__global__ __launch_bounds__(1024) void gcn_phase1_kernel(
    const float* __restrict__ x, const float* __restrict__ w,
    __hip_bfloat16* __restrict__ support,
    const int* __restrict__ esrc, const int* __restrict__ edst,
    const float* __restrict__ ew, int* __restrict__ bcount,
    int2* __restrict__ region, int n_nodes, int n_edges, int nb,
    int n_scat_blocks) {
  __shared__ Phase1Smem sm;
  const int tid = threadIdx.x;

  if ((int)blockIdx.x < n_scat_blocks) {
    // ---------------- scatter body: edges in registers ----------------
    const int e0 = blockIdx.x * SCAT_CHUNK;
    const int n_local = min(SCAT_CHUNK, n_edges - e0);

    for (int i = tid; i < nb; i += 1024) sm.s.lhist[i] = 0;
    __syncthreads();
    int dreg[EPT];
#pragma unroll
    for (int p = 0; p < EPT; ++p) {
      const int i = tid + p * 1024;
      dreg[p] = -1;
      if (i < n_local) {
        const int d = edst[e0 + i];
        dreg[p] = d;
        atomicAdd(&sm.s.lhist[d >> BUCKET_SHIFT], 1);
      }
    }
    __syncthreads();
    for (int b = tid; b < nb; b += 1024) {
      const int c = sm.s.lhist[b];
      const int rc = (c + 7) & ~7;  // round run to 64B lines
      sm.s.lcur[b] = rc ? atomicAdd(&bcount[b * CNT_STRIDE], rc) : 0;
    }
    __syncthreads();
#pragma unroll
    for (int p = 0; p < EPT; ++p) {
      const int i = tid + p * 1024;
      const int d = dreg[p];
      if (d >= 0) {
        const int b = d >> BUCKET_SHIFT;
        const int pos = atomicAdd(&sm.s.lcur[b], 1);  // native int LDS atomic
        if (pos < BUCKET_CAP) {
          region[(size_t)b * BUCKET_CAP + pos] = make_int2(
              (esrc[e0 + i] << BUCKET_SHIFT) | (d & (BUCKET_NODES - 1)),
              __float_as_int(ew[e0 + i]));
        }
      }
    }
    __syncthreads();
    // pad fill: lcur[b] = base + c; npad = (8 - (c&7)) & 7 completes the line.
    for (int b = tid; b < nb; b += 1024) {
      const int c = sm.s.lhist[b];
      const int npad = (8 - (c & 7)) & 7;
      const int start = sm.s.lcur[b];
      for (int k = 0; k < npad; ++k) {
        const int pos = start + k;
        if (pos < BUCKET_CAP)
          region[(size_t)b * BUCKET_CAP + pos] =
              make_int2(pos & (BUCKET_NODES - 1), 0);  // src=0, w=0: adds 0
      }
    }
  } else {
    // ------ GEMM body: 128 rows, 16 waves = 8 row-groups x 2 col-halves -----
    const int gbid = (int)blockIdx.x - n_scat_blocks;
    const int block_row = gbid * P1_GEMM_ROWS;

#pragma unroll
    for (int i = 0; i < F_IN * F_OUT / 1024; ++i) {  // 8 iters
      const int idx = tid + i * 1024;
      sm.g.Bs[idx & 63][idx >> 6] = bf16_bits(w[idx]);
    }

    const int lane = tid & 63;
    const int wid = tid >> 6;
    const int wr0 = (wid >> 1) * 16;  // row group (0..112)
    const int wc0 = (wid & 1) * 32;   // col half
    const int m = lane & 15;
    const int quad = lane >> 4;
    const int row = block_row + wr0 + m;

    // A-fragments straight from global: 8 contiguous K elems per lane per ks.
    bf16x8 afrag[4];
    if (row < n_nodes) {
      const float4* xr = (const float4*)(x + (size_t)row * F_IN);
#pragma unroll
      for (int ks = 0; ks < 4; ++ks) {
        const float4 v0 = xr[ks * 8 + quad * 2];
        const float4 v1 = xr[ks * 8 + quad * 2 + 1];
        bf16x8 a;
        a[0] = bf16_bits(v0.x); a[1] = bf16_bits(v0.y);
        a[2] = bf16_bits(v0.z); a[3] = bf16_bits(v0.w);
        a[4] = bf16_bits(v1.x); a[5] = bf16_bits(v1.y);
        a[6] = bf16_bits(v1.z); a[7] = bf16_bits(v1.w);
        afrag[ks] = a;
      }
    } else {
#pragma unroll
      for (int ks = 0; ks < 4; ++ks) afrag[ks] = (bf16x8)0;
    }
    __syncthreads();  // Bs ready

    f32x4 acc0 = {0.f, 0.f, 0.f, 0.f};
    f32x4 acc1 = {0.f, 0.f, 0.f, 0.f};
#pragma unroll
    for (int ks = 0; ks < 4; ++ks) {
      const int ko = ks * 32 + quad * 8;
      const bf16x8 b0 = *(const bf16x8*)&sm.g.Bs[wc0 + m][ko];
      const bf16x8 b1 = *(const bf16x8*)&sm.g.Bs[wc0 + 16 + m][ko];
      acc0 = __builtin_amdgcn_mfma_f32_16x16x32_bf16(afrag[ks], b0, acc0, 0, 0, 0);
      acc1 = __builtin_amdgcn_mfma_f32_16x16x32_bf16(afrag[ks], b1, acc1, 0, 0, 0);
    }
#pragma unroll
    for (int r = 0; r < 4; ++r) {
      const int orow = block_row + wr0 + quad * 4 + r;
      if (orow < n_nodes) {
        __hip_bfloat16* op = support + (size_t)orow * F_OUT;
        op[wc0 + m]      = __float2bfloat16(acc0[r]);
        op[wc0 + 16 + m] = __float2bfloat16(acc1[r]);
      }
    }
  }
}

// -------- pass 2: per-bucket LDS sort + in-kernel aggregate, 1024 thr --------
// Gather loop unrolled x2 (16-edge steps): typical run (deg~16) completes in
// ONE ds_read->VMEM dependency chain; dual f32 accumulator banks.
__global__ __launch_bounds__(1024) void gcn_sort_agg_kernel(
    const __hip_bfloat16* __restrict__ support,
    const int2* __restrict__ region, const int* __restrict__ bcount,
    const float* __restrict__ bias, float* __restrict__ out, int n_nodes) {
  __shared__ int2 outb[BUCKET_CAP];          // 23040 B
  __shared__ int hist4[4][BUCKET_NODES];     //  2048 B
  __shared__ int nbeg[BUCKET_NODES];
  __shared__ int lcur[BUCKET_NODES];
  const int b = blockIdx.x;
  const int tid = threadIdx.x;
  const int lane = tid & 63;
  const int hq = (tid >> 6) & 3;  // wave-granular hist copy

  int cnt = bcount[b * CNT_STRIDE];
  cnt = (cnt < BUCKET_CAP ? cnt : BUCKET_CAP);
  const int2* reg = region + (size_t)b * BUCKET_CAP;

  for (int i = tid; i < 4 * BUCKET_NODES; i += 1024) ((int*)hist4)[i] = 0;
  __syncthreads();
  int2 ereg[SA_EPT];
#pragma unroll
  for (int p = 0; p < SA_EPT; ++p) {          // single region read -> regs
    const int i = tid + p * 1024;
    ereg[p].x = -1;
    if (i < cnt) {
      ereg[p] = reg[i];
      atomicAdd(&hist4[hq][ereg[p].x & (BUCKET_NODES - 1)], 1);
    }
  }
  __syncthreads();
  if (tid < 64) {                             // exclusive scan of 128 counts
    const int v0 = hist4[0][lane] + hist4[1][lane] + hist4[2][lane] +
                   hist4[3][lane];
    const int l1 = 64 + lane;
    const int v1 = hist4[0][l1] + hist4[1][l1] + hist4[2][l1] + hist4[3][l1];
    int s0 = v0;
#pragma unroll
    for (int off = 1; off < 64; off <<= 1) {
      const int t = __shfl_up(s0, off, 64);
      if (lane >= off) s0 += t;
    }
    const int tot0 = __shfl(s0, 63, 64);
    int s1 = v1;
#pragma unroll
    for (int off = 1; off < 64; off <<= 1) {
      const int t = __shfl_up(s1, off, 64);
      if (lane >= off) s1 += t;
    }
    s1 += tot0;
    nbeg[lane] = s0 - v0;
    nbeg[l1] = s1 - v1;
    lcur[lane] = s0 - v0;
    lcur[l1] = s1 - v1;
  }
  __syncthreads();
#pragma unroll
  for (int p = 0; p < SA_EPT; ++p) {          // scatter into outb from regs
    if (ereg[p].x >= 0) {
      const int pos = atomicAdd(&lcur[ereg[p].x & (BUCKET_NODES - 1)], 1);
      outb[pos] = make_int2(ereg[p].x >> BUCKET_SHIFT, ereg[p].y);
    }
  }
  __syncthreads();                            // lcur[n] now == run end

  // aggregate: wave owns 8 nodes; lane = (row-slot r=lane>>3, chan-grp lane&7)
  const int wid = tid >> 6;
  const int r = lane >> 3;
  const int cg = lane & 7;
  const ushort* sup = (const ushort*)support;
  const float4 bb0 = *(const float4*)(bias + cg * 8);
  const float4 bb1 = *(const float4*)(bias + cg * 8 + 4);
  for (int nl = wid * 8; nl < wid * 8 + 8; ++nl) {
    const int g = (b << BUCKET_SHIFT) + nl;
    if (g >= n_nodes) break;  // uniform across wave
    const int s = nbeg[nl];
    const int e = lcur[nl];
    float acc0[8] = {0.f, 0.f, 0.f, 0.f, 0.f, 0.f, 0.f, 0.f};
    float acc1[8] = {0.f, 0.f, 0.f, 0.f, 0.f, 0.f, 0.f, 0.f};
    for (int j = s; j < e; j += 16) {
      const int jr0 = j + r;
      const int jr1 = j + 8 + r;
      const bool v0 = jr0 < e;
      const bool v1 = jr1 < e;
      const int2 m0 = outb[v0 ? jr0 : s];
      const int2 m1 = outb[v1 ? jr1 : s];
      const float w0 = v0 ? __int_as_float(m0.y) : 0.f;
      const float w1 = v1 ? __int_as_float(m1.y) : 0.f;
      const uint4 d0 = *(const uint4*)(sup + (size_t)m0.x * F_OUT + cg * 8);
      const uint4 d1 = *(const uint4*)(sup + (size_t)m1.x * F_OUT + cg * 8);
      acc0[0] = fmaf(__uint_as_float(d0.x << 16), w0, acc0[0]);
      acc0[1] = fmaf(__uint_as_float(d0.x & 0xffff0000u), w0, acc0[1]);
      acc0[2] = fmaf(__uint_as_float(d0.y << 16), w0, acc0[2]);
      acc0[3] = fmaf(__uint_as_float(d0.y & 0xffff0000u), w0, acc0[3]);
      acc0[4] = fmaf(__uint_as_float(d0.z << 16), w0, acc0[4]);
      acc0[5] = fmaf(__uint_as_float(d0.z & 0xffff0000u), w0, acc0[5]);
      acc0[6] = fmaf(__uint_as_float(d0.w << 16), w0, acc0[6]);
      acc0[7] = fmaf(__uint_as_float(d0.w & 0xffff0000u), w0, acc0[7]);
      acc1[0] = fmaf(__uint_as_float(d1.x << 16), w1, acc1[0]);
      acc1[1] = fmaf(__uint_as_float(d1.x & 0xffff0000u), w1, acc1[1]);
      acc1[2] = fmaf(__uint_as_float(d1.y << 16), w1, acc1[2]);
      acc1[3] = fmaf(__uint_as_float(d1.y & 0xffff0000u), w1, acc1[3]);
      acc1[4] = fmaf(__uint_as_float(d1.z << 16), w1, acc1[4]);
      acc1[5] = fmaf(__uint_as_float(d1.z & 0xffff0000u), w1, acc1[5]);
      acc1[6] = fmaf(__uint_as_float(d1.w << 16), w1, acc1[6]);
      acc1[7] = fmaf(__uint_as_float(d1.w & 0xffff0000u), w1, acc1[7]);
    }
#pragma unroll
    for (int i = 0; i < 8; ++i) {  // reduce over the 8 row-slots
      float v = acc0[i] + acc1[i];
      v += __shfl_xor(v, 8, 64);
      v += __shfl_xor(v, 16, 64);
      v += __shfl_xor(v, 32, 64);
      acc0[i] = v;
    }
    if (r == 0) {
      float* op = out + (size_t)g * F_OUT + cg * 8;
      float4 o0, o1;
      o0.x = acc0[0] + bb0.x; o0.y = acc0[1] + bb0.y;
      o0.z = acc0[2] + bb0.z; o0.w = acc0[3] + bb0.w;
      o1.x = acc0[4] + bb1.x; o1.y = acc0[5] + bb1.y;
      o1.z = acc0[6] + bb1.z; o1.w = acc0[7] + bb1.w;
      *(float4*)op = o0;
      *(float4*)(op + 4) = o1;
    }
  }
}

extern "C" void kernel_launch(void* const* d_in, const int* in_sizes, int n_in,
                              void* d_out, int out_size, void* d_ws, size_t ws_size,
                              hipStream_t stream) {
  const float* x    = (const float*)d_in[0];
  const float* ew   = (const float*)d_in[1];
  const float* w    = (const float*)d_in[2];
  const float* bias = (const float*)d_in[3];
  const int*   esrc = (const int*)d_in[4];
  const int*   edst = (const int*)d_in[5];
  float* out = (float*)d_out;

  const int n_nodes = in_sizes[0] / F_IN;
  const int n_edges = in_sizes[4];
  const int nb = (n_nodes + BUCKET_NODES - 1) >> BUCKET_SHIFT;

  // workspace: bcount | region | support  (~31 MB)
  char* ws = (char*)d_ws;
  size_t off = 0;
  auto alloc = [&](size_t bytes) {
    size_t o = off;
    off += (bytes + 255) / 256 * 256;
    return o;
  };
  const size_t off_bcount  = alloc((size_t)nb * CNT_STRIDE * sizeof(int));
  const size_t off_region  = alloc((size_t)nb * BUCKET_CAP * sizeof(int2));
  const size_t off_support = alloc((size_t)n_nodes * F_OUT * sizeof(__hip_bfloat16));
  (void)off_support;

  int*  bcount = (int*)(ws + off_bcount);
  int2* region = (int2*)(ws + off_region);
  __hip_bfloat16* support = (__hip_bfloat16*)(ws + off_support);

  const int scat_blocks = (n_edges + SCAT_CHUNK - 1) / SCAT_CHUNK;
  const int gemm_blocks = (n_nodes + P1_GEMM_ROWS - 1) / P1_GEMM_ROWS;

  hipMemsetAsync(bcount, 0, (size_t)nb * CNT_STRIDE * sizeof(int), stream);
  gcn_phase1_kernel<<<scat_blocks + gemm_blocks, 1024, 0, stream>>>(
      x, w, support, esrc, edst, ew, bcount, region, n_nodes, n_edges, nb,
      scat_blocks);
  gcn_sort_agg_kernel<<<nb, 1024, 0, stream>>>(support, region, bcount, bias,
                                               out, n_nodes);
}

// Round 7
// 182.840 us; speedup vs baseline: 1.1335x; 1.0660x over previous
//
#include <hip/hip_runtime.h>
#include <hip/hip_bf16.h>

#define F_IN 128
#define F_OUT 64
#define BUCKET_SHIFT 7
#define BUCKET_NODES 128   // 1 << BUCKET_SHIFT
#define BUCKET_CAP 2880    // per bucket: mean 2048, sigma ~45 -> 18 sigma margin
#define CNT_STRIDE 16      // bucket counters padded to one 64B line
#define NB_MAX 800         // ceil(100000/128) = 782
#define SCAT_CHUNK 4096    // edges per scatter block (fits LDS bucket-sort)
#define EPT 4              // edges per thread in scatter (SCAT_CHUNK/1024)
#define P1_GEMM_ROWS 128   // rows per GEMM tile (1024 thr: 8 row-grp x 2 col)
#define LDK 136            // padded K stride in LDS (elems): 272B = 17*16B
#define SA_EPT 3           // region entries per thread in sort_agg (2880/1024)

typedef __attribute__((ext_vector_type(8))) short bf16x8;
typedef __attribute__((ext_vector_type(4))) float f32x4;

__device__ inline short bf16_bits(float f) {
  __hip_bfloat16 h = __float2bfloat16(f);
  return *reinterpret_cast<short*>(&h);
}

// ---------------- phase 1: fused {bucket scatter | GEMM}, 1024 threads ------
// R6 falsified write-TRAFFIC as the limiter; the wall is scattered-store
// TRANSACTIONS (64 lanes -> 64 lines per store inst). Fix: bucket-sort the
// chunk in LDS (ebuf) first, then write region with a LANE-CONTIGUOUS sweep:
// one store inst covers 64 consecutive slots = ~12 contiguous run segments
// -> ~5x fewer scattered-store transactions.
union Phase1Smem {
  struct { short Bs[F_OUT][LDK]; } g;                  // 17408 B
  struct {
    int2 ebuf[SCAT_CHUNK];   // 32768 B  bucket-sorted edge payloads
    int  gaddr[SCAT_CHUNK];  // 16384 B  final global region index per slot
    int  lhist[NB_MAX];      //  3200 B
    int  lbeg[NB_MAX];       //  3200 B
    int  lcur[NB_MAX];       //  3200 B
    int  gbase[NB_MAX];      //  3200 B
    int  wtot[16];
  } s;                       // ~62 KB -> 2 blocks/CU
};

__global__ __launch_bounds__(1024) void gcn_phase1_kernel(
    const float* __restrict__ x, const float* __restrict__ w,
    __hip_bfloat16* __restrict__ support,
    const int* __restrict__ esrc, const int* __restrict__ edst,
    const float* __restrict__ ew, int* __restrict__ bcount,
    int2* __restrict__ region, int n_nodes, int n_edges, int nb,
    int n_scat_blocks) {
  __shared__ Phase1Smem sm;
  const int tid = threadIdx.x;
  const int lane = tid & 63;
  const int wid = tid >> 6;

  if ((int)blockIdx.x < n_scat_blocks) {
    // ---------------- scatter body: LDS bucket-sort then coalesced write ----
    const int e0 = blockIdx.x * SCAT_CHUNK;
    const int n_local = min(SCAT_CHUNK, n_edges - e0);

    for (int i = tid; i < nb; i += 1024) sm.s.lhist[i] = 0;
    __syncthreads();
    int dreg[EPT];
#pragma unroll
    for (int p = 0; p < EPT; ++p) {
      const int i = tid + p * 1024;
      dreg[p] = -1;
      if (i < n_local) {
        const int d = edst[e0 + i];
        dreg[p] = d;
        atomicAdd(&sm.s.lhist[d >> BUCKET_SHIFT], 1);
      }
    }
    __syncthreads();
    // block-wide exclusive scan over bucket counts (one bucket per thread)
    const int c = (tid < nb) ? sm.s.lhist[tid] : 0;
    int sc = c;
#pragma unroll
    for (int off = 1; off < 64; off <<= 1) {
      const int t = __shfl_up(sc, off, 64);
      if (lane >= off) sc += t;
    }
    if (lane == 63) sm.s.wtot[wid] = sc;
    __syncthreads();
    if (wid == 0) {
      const int wv = (lane < 16) ? sm.s.wtot[lane] : 0;
      int ws = wv;
#pragma unroll
      for (int off = 1; off < 16; off <<= 1) {
        const int t = __shfl_up(ws, off, 64);
        if (lane >= off) ws += t;
      }
      if (lane < 16) sm.s.wtot[lane] = ws - wv;
    }
    __syncthreads();
    if (tid < nb) {
      const int beg = (sc - c) + sm.s.wtot[wid];
      sm.s.lbeg[tid] = beg;
      sm.s.lcur[tid] = beg;
      sm.s.gbase[tid] = c ? atomicAdd(&bcount[tid * CNT_STRIDE], c) : 0;
    }
    __syncthreads();
    // scatter into ebuf in bucket order; record final global slot
#pragma unroll
    for (int p = 0; p < EPT; ++p) {
      const int i = tid + p * 1024;
      const int d = dreg[p];
      if (d >= 0) {
        const int b = d >> BUCKET_SHIFT;
        const int pos = atomicAdd(&sm.s.lcur[b], 1);  // native int LDS atomic
        const int slot = sm.s.gbase[b] + (pos - sm.s.lbeg[b]);
        sm.s.ebuf[pos] = make_int2(
            (esrc[e0 + i] << BUCKET_SHIFT) | (d & (BUCKET_NODES - 1)),
            __float_as_int(ew[e0 + i]));
        sm.s.gaddr[pos] = (slot < BUCKET_CAP) ? b * BUCKET_CAP + slot : -1;
      }
    }
    __syncthreads();
    // lane-contiguous sweep: consecutive lanes -> consecutive slots ->
    // (mostly) contiguous region addresses. ~12 line txns/inst vs 64 before.
#pragma unroll
    for (int p = 0; p < EPT; ++p) {
      const int i = tid + p * 1024;
      if (i < n_local) {
        const int ga = sm.s.gaddr[i];
        if (ga >= 0) region[ga] = sm.s.ebuf[i];
      }
    }
  } else {
    // ------ GEMM body: 128 rows, 16 waves = 8 row-groups x 2 col-halves -----
    const int gbid = (int)blockIdx.x - n_scat_blocks;
    const int block_row = gbid * P1_GEMM_ROWS;

#pragma unroll
    for (int i = 0; i < F_IN * F_OUT / 1024; ++i) {  // 8 iters
      const int idx = tid + i * 1024;
      sm.g.Bs[idx & 63][idx >> 6] = bf16_bits(w[idx]);
    }

    const int wr0 = (wid >> 1) * 16;  // row group (0..112)
    const int wc0 = (wid & 1) * 32;   // col half
    const int m = lane & 15;
    const int quad = lane >> 4;
    const int row = block_row + wr0 + m;

    // A-fragments straight from global: 8 contiguous K elems per lane per ks.
    bf16x8 afrag[4];
    if (row < n_nodes) {
      const float4* xr = (const float4*)(x + (size_t)row * F_IN);
#pragma unroll
      for (int ks = 0; ks < 4; ++ks) {
        const float4 v0 = xr[ks * 8 + quad * 2];
        const float4 v1 = xr[ks * 8 + quad * 2 + 1];
        bf16x8 a;
        a[0] = bf16_bits(v0.x); a[1] = bf16_bits(v0.y);
        a[2] = bf16_bits(v0.z); a[3] = bf16_bits(v0.w);
        a[4] = bf16_bits(v1.x); a[5] = bf16_bits(v1.y);
        a[6] = bf16_bits(v1.z); a[7] = bf16_bits(v1.w);
        afrag[ks] = a;
      }
    } else {
#pragma unroll
      for (int ks = 0; ks < 4; ++ks) afrag[ks] = (bf16x8)0;
    }
    __syncthreads();  // Bs ready

    f32x4 acc0 = {0.f, 0.f, 0.f, 0.f};
    f32x4 acc1 = {0.f, 0.f, 0.f, 0.f};
#pragma unroll
    for (int ks = 0; ks < 4; ++ks) {
      const int ko = ks * 32 + quad * 8;
      const bf16x8 b0 = *(const bf16x8*)&sm.g.Bs[wc0 + m][ko];
      const bf16x8 b1 = *(const bf16x8*)&sm.g.Bs[wc0 + 16 + m][ko];
      acc0 = __builtin_amdgcn_mfma_f32_16x16x32_bf16(afrag[ks], b0, acc0, 0, 0, 0);
      acc1 = __builtin_amdgcn_mfma_f32_16x16x32_bf16(afrag[ks], b1, acc1, 0, 0, 0);
    }
#pragma unroll
    for (int r = 0; r < 4; ++r) {
      const int orow = block_row + wr0 + quad * 4 + r;
      if (orow < n_nodes) {
        __hip_bfloat16* op = support + (size_t)orow * F_OUT;
        op[wc0 + m]      = __float2bfloat16(acc0[r]);
        op[wc0 + 16 + m] = __float2bfloat16(acc1[r]);
      }
    }
  }
}

// -------- pass 2: per-bucket LDS sort + in-kernel aggregate, 1024 thr --------
// (unchanged from R6: single region read into regs, 4-way privatized hist,
// 8 row-slots x 8 channel-groups gather, x2 unroll / dual accumulator banks)
__global__ __launch_bounds__(1024) void gcn_sort_agg_kernel(
    const __hip_bfloat16* __restrict__ support,
    const int2* __restrict__ region, const int* __restrict__ bcount,
    const float* __restrict__ bias, float* __restrict__ out, int n_nodes) {
  __shared__ int2 outb[BUCKET_CAP];          // 23040 B
  __shared__ int hist4[4][BUCKET_NODES];     //  2048 B
  __shared__ int nbeg[BUCKET_NODES];
  __shared__ int lcur[BUCKET_NODES];
  const int b = blockIdx.x;
  const int tid = threadIdx.x;
  const int lane = tid & 63;
  const int hq = (tid >> 6) & 3;  // wave-granular hist copy

  int cnt = bcount[b * CNT_STRIDE];
  cnt = (cnt < BUCKET_CAP ? cnt : BUCKET_CAP);
  const int2* reg = region + (size_t)b * BUCKET_CAP;

  for (int i = tid; i < 4 * BUCKET_NODES; i += 1024) ((int*)hist4)[i] = 0;
  __syncthreads();
  int2 ereg[SA_EPT];
#pragma unroll
  for (int p = 0; p < SA_EPT; ++p) {          // single region read -> regs
    const int i = tid + p * 1024;
    ereg[p].x = -1;
    if (i < cnt) {
      ereg[p] = reg[i];
      atomicAdd(&hist4[hq][ereg[p].x & (BUCKET_NODES - 1)], 1);
    }
  }
  __syncthreads();
  if (tid < 64) {                             // exclusive scan of 128 counts
    const int v0 = hist4[0][lane] + hist4[1][lane] + hist4[2][lane] +
                   hist4[3][lane];
    const int l1 = 64 + lane;
    const int v1 = hist4[0][l1] + hist4[1][l1] + hist4[2][l1] + hist4[3][l1];
    int s0 = v0;
#pragma unroll
    for (int off = 1; off < 64; off <<= 1) {
      const int t = __shfl_up(s0, off, 64);
      if (lane >= off) s0 += t;
    }
    const int tot0 = __shfl(s0, 63, 64);
    int s1 = v1;
#pragma unroll
    for (int off = 1; off < 64; off <<= 1) {
      const int t = __shfl_up(s1, off, 64);
      if (lane >= off) s1 += t;
    }
    s1 += tot0;
    nbeg[lane] = s0 - v0;
    nbeg[l1] = s1 - v1;
    lcur[lane] = s0 - v0;
    lcur[l1] = s1 - v1;
  }
  __syncthreads();
#pragma unroll
  for (int p = 0; p < SA_EPT; ++p) {          // scatter into outb from regs
    if (ereg[p].x >= 0) {
      const int pos = atomicAdd(&lcur[ereg[p].x & (BUCKET_NODES - 1)], 1);
      outb[pos] = make_int2(ereg[p].x >> BUCKET_SHIFT, ereg[p].y);
    }
  }
  __syncthreads();                            // lcur[n] now == run end

  // aggregate: wave owns 8 nodes; lane = (row-slot r=lane>>3, chan-grp lane&7)
  const int wid = tid >> 6;
  const int r = lane >> 3;
  const int cg = lane & 7;
  const ushort* sup = (const ushort*)support;
  const float4 bb0 = *(const float4*)(bias + cg * 8);
  const float4 bb1 = *(const float4*)(bias + cg * 8 + 4);
  for (int nl = wid * 8; nl < wid * 8 + 8; ++nl) {
    const int g = (b << BUCKET_SHIFT) + nl;
    if (g >= n_nodes) break;  // uniform across wave
    const int s = nbeg[nl];
    const int e = lcur[nl];
    float acc0[8] = {0.f, 0.f, 0.f, 0.f, 0.f, 0.f, 0.f, 0.f};
    float acc1[8] = {0.f, 0.f, 0.f, 0.f, 0.f, 0.f, 0.f, 0.f};
    for (int j = s; j < e; j += 16) {
      const int jr0 = j + r;
      const int jr1 = j + 8 + r;
      const bool v0 = jr0 < e;
      const bool v1 = jr1 < e;
      const int2 m0 = outb[v0 ? jr0 : s];
      const int2 m1 = outb[v1 ? jr1 : s];
      const float w0 = v0 ? __int_as_float(m0.y) : 0.f;
      const float w1 = v1 ? __int_as_float(m1.y) : 0.f;
      const uint4 d0 = *(const uint4*)(sup + (size_t)m0.x * F_OUT + cg * 8);
      const uint4 d1 = *(const uint4*)(sup + (size_t)m1.x * F_OUT + cg * 8);
      acc0[0] = fmaf(__uint_as_float(d0.x << 16), w0, acc0[0]);
      acc0[1] = fmaf(__uint_as_float(d0.x & 0xffff0000u), w0, acc0[1]);
      acc0[2] = fmaf(__uint_as_float(d0.y << 16), w0, acc0[2]);
      acc0[3] = fmaf(__uint_as_float(d0.y & 0xffff0000u), w0, acc0[3]);
      acc0[4] = fmaf(__uint_as_float(d0.z << 16), w0, acc0[4]);
      acc0[5] = fmaf(__uint_as_float(d0.z & 0xffff0000u), w0, acc0[5]);
      acc0[6] = fmaf(__uint_as_float(d0.w << 16), w0, acc0[6]);
      acc0[7] = fmaf(__uint_as_float(d0.w & 0xffff0000u), w0, acc0[7]);
      acc1[0] = fmaf(__uint_as_float(d1.x << 16), w1, acc1[0]);
      acc1[1] = fmaf(__uint_as_float(d1.x & 0xffff0000u), w1, acc1[1]);
      acc1[2] = fmaf(__uint_as_float(d1.y << 16), w1, acc1[2]);
      acc1[3] = fmaf(__uint_as_float(d1.y & 0xffff0000u), w1, acc1[3]);
      acc1[4] = fmaf(__uint_as_float(d1.z << 16), w1, acc1[4]);
      acc1[5] = fmaf(__uint_as_float(d1.z & 0xffff0000u), w1, acc1[5]);
      acc1[6] = fmaf(__uint_as_float(d1.w << 16), w1, acc1[6]);
      acc1[7] = fmaf(__uint_as_float(d1.w & 0xffff0000u), w1, acc1[7]);
    }
#pragma unroll
    for (int i = 0; i < 8; ++i) {  // reduce over the 8 row-slots
      float v = acc0[i] + acc1[i];
      v += __shfl_xor(v, 8, 64);
      v += __shfl_xor(v, 16, 64);
      v += __shfl_xor(v, 32, 64);
      acc0[i] = v;
    }
    if (r == 0) {
      float* op = out + (size_t)g * F_OUT + cg * 8;
      float4 o0, o1;
      o0.x = acc0[0] + bb0.x; o0.y = acc0[1] + bb0.y;
      o0.z = acc0[2] + bb0.z; o0.w = acc0[3] + bb0.w;
      o1.x = acc0[4] + bb1.x; o1.y = acc0[5] + bb1.y;
      o1.z = acc0[6] + bb1.z; o1.w = acc0[7] + bb1.w;
      *(float4*)op = o0;
      *(float4*)(op + 4) = o1;
    }
  }
}

extern "C" void kernel_launch(void* const* d_in, const int* in_sizes, int n_in,
                              void* d_out, int out_size, void* d_ws, size_t ws_size,
                              hipStream_t stream) {
  const float* x    = (const float*)d_in[0];
  const float* ew   = (const float*)d_in[1];
  const float* w    = (const float*)d_in[2];
  const float* bias = (const float*)d_in[3];
  const int*   esrc = (const int*)d_in[4];
  const int*   edst = (const int*)d_in[5];
  float* out = (float*)d_out;

  const int n_nodes = in_sizes[0] / F_IN;
  const int n_edges = in_sizes[4];
  const int nb = (n_nodes + BUCKET_NODES - 1) >> BUCKET_SHIFT;

  // workspace: bcount | region | support  (~31 MB)
  char* ws = (char*)d_ws;
  size_t off = 0;
  auto alloc = [&](size_t bytes) {
    size_t o = off;
    off += (bytes + 255) / 256 * 256;
    return o;
  };
  const size_t off_bcount  = alloc((size_t)nb * CNT_STRIDE * sizeof(int));
  const size_t off_region  = alloc((size_t)nb * BUCKET_CAP * sizeof(int2));
  const size_t off_support = alloc((size_t)n_nodes * F_OUT * sizeof(__hip_bfloat16));
  (void)off_support;

  int*  bcount = (int*)(ws + off_bcount);
  int2* region = (int2*)(ws + off_region);
  __hip_bfloat16* support = (__hip_bfloat16*)(ws + off_support);

  const int scat_blocks = (n_edges + SCAT_CHUNK - 1) / SCAT_CHUNK;
  const int gemm_blocks = (n_nodes + P1_GEMM_ROWS - 1) / P1_GEMM_ROWS;

  hipMemsetAsync(bcount, 0, (size_t)nb * CNT_STRIDE * sizeof(int), stream);
  gcn_phase1_kernel<<<scat_blocks + gemm_blocks, 1024, 0, stream>>>(
      x, w, support, esrc, edst, ew, bcount, region, n_nodes, n_edges, nb,
      scat_blocks);
  gcn_sort_agg_kernel<<<nb, 1024, 0, stream>>>(support, region, bcount, bias,
                                               out, n_nodes);
}